// Round 13
// baseline (792.731 us; speedup 1.0000x reference)
//
#include <hip/hip_runtime.h>
#include <hip/hip_bf16.h>
#include <math.h>

#define WAVE 64
#define GR 64   // rows per GEMM tile block

typedef __attribute__((ext_vector_type(8))) short bf16x8;
typedef __attribute__((ext_vector_type(4))) float f32x4;

// round-to-nearest-even fp32 -> bf16
__device__ __forceinline__ unsigned short f2bf(float x) {
    unsigned int b = __float_as_uint(x);
    unsigned int r = b + 0x7FFFu + ((b >> 16) & 1u);
    return (unsigned short)(r >> 16);
}
__device__ __forceinline__ float bf2f(unsigned short h) {
    return __uint_as_float(((unsigned int)h) << 16);
}

// ---------------- CSR build: count (2 edges/thread) + W-pack fused ----------------
// blocks [0,nbC): degree count; [nbC,nbC+128): W1/W2 B-fragment pack.
__global__ void count_pack(const int* __restrict__ dst, int* __restrict__ deg, int E, int nbC,
                           const float* __restrict__ W1, const float* __restrict__ W2,
                           unsigned short* __restrict__ W1hi, unsigned short* __restrict__ W1lo,
                           unsigned short* __restrict__ W2hi, unsigned short* __restrict__ W2lo) {
    int b = blockIdx.x;
    if (b < nbC) {
        int e = (b * 256 + threadIdx.x) * 2;
        if (e + 1 < E) {
            int2 d = *(const int2*)(dst + e);
            atomicAdd(&deg[d.x], 1);
            atomicAdd(&deg[d.y], 1);
        } else if (e < E) {
            atomicAdd(&deg[dst[e]], 1);
        }
    } else {
        int pb = b - nbC;   // 0..127: first 64 -> W1, next 64 -> W2
        const float* W = (pb >= 64) ? W2 : W1;
        unsigned short* Hi = (pb >= 64) ? W2hi : W1hi;
        unsigned short* Lo = (pb >= 64) ? W2lo : W1lo;
        int idx = (pb & 63) * 256 + threadIdx.x;   // 0..16383
        int j = idx & 7;
        int lane = (idx >> 3) & 63;
        int kc = (idx >> 9) & 3;
        int nt = idx >> 11;
        int k = kc * 32 + (lane >> 4) * 8 + j;
        int ncol = nt * 16 + (lane & 15);
        float x = W[k * 128 + ncol];
        unsigned short h = f2bf(x);
        Hi[idx] = h;
        Lo[idx] = f2bf(x - bf2f(h));
    }
}

__global__ void scan_block(const int* __restrict__ in, int* __restrict__ part,
                           int* __restrict__ bsums, int n) {
    __shared__ int tmp[256];
    int tid = threadIdx.x;
    int i = blockIdx.x * 256 + tid;
    int v = (i < n) ? in[i] : 0;
    tmp[tid] = v;
    __syncthreads();
    for (int o = 1; o < 256; o <<= 1) {
        int t = (tid >= o) ? tmp[tid - o] : 0;
        __syncthreads();
        tmp[tid] += t;
        __syncthreads();
    }
    if (i < n) part[i] = tmp[tid] - v;
    if (tid == 255) bsums[blockIdx.x] = tmp[255];
}

__global__ void scan_finish(const int* __restrict__ part, const int* __restrict__ bsums,
                            int* __restrict__ offs, int* __restrict__ cursor,
                            int n, int Etot) {
    __shared__ int acc[256];
    int b = blockIdx.x, tid = threadIdx.x;
    int s = 0;
    for (int i = tid; i < b; i += 256) s += bsums[i];
    acc[tid] = s;
    __syncthreads();
    for (int o = 128; o > 0; o >>= 1) {
        if (tid < o) acc[tid] += acc[tid + o];
        __syncthreads();
    }
    int prefix = acc[0];
    int i = b * 256 + tid;
    if (i < n) {
        int v = part[i] + prefix;
        offs[i] = v;
        cursor[i] = v;
    }
    if (b == 0 && tid == 0) offs[n] = Etot;
}

__global__ void scatter_edges(const int* __restrict__ src, const int* __restrict__ dst,
                              int* __restrict__ cursor, int* __restrict__ csr_src, int E) {
    int e = (blockIdx.x * 256 + threadIdx.x) * 2;
    if (e + 1 < E) {
        int2 d = *(const int2*)(dst + e);
        int2 s = *(const int2*)(src + e);
        int p0 = atomicAdd(&cursor[d.x], 1);
        csr_src[p0] = s.x;
        int p1 = atomicAdd(&cursor[d.y], 1);
        csr_src[p1] = s.y;
    } else if (e < E) {
        int p = atomicAdd(&cursor[dst[e]], 1);
        csr_src[p] = src[e];
    }
}

// ---------------- MFMA GEMM (bf16x3 split) + attention dots fused (round-8, measured-good) ----------------
__global__ __launch_bounds__(256) void gemm_mfma(const float* __restrict__ X,
                                                 const unsigned short* __restrict__ Bhi,
                                                 const unsigned short* __restrict__ Blo,
                                                 const float* __restrict__ a_s,
                                                 const float* __restrict__ a_d,
                                                 float* __restrict__ Hout,
                                                 float* __restrict__ as_,
                                                 float* __restrict__ ad_, int n) {
    __shared__ char lds[64 * 136 * 4];   // Xhi+Xlo (bf16) then reused as Hs (fp32)
    unsigned short* Xhi = (unsigned short*)lds;
    unsigned short* Xlo = Xhi + 64 * 136;
    float* Hs = (float*)lds;

    int tid = threadIdx.x;
    int base = blockIdx.x * GR;
    const float4* X4 = (const float4*)X;

#pragma unroll
    for (int i = 0; i < 8; ++i) {
        int idx = i * 256 + tid;
        int row = idx >> 5, c4 = idx & 31;
        int rs = base + row; if (rs >= n) rs = n - 1;
        float4 v = X4[(size_t)rs * 32 + c4];
        unsigned short h0 = f2bf(v.x), h1 = f2bf(v.y), h2 = f2bf(v.z), h3 = f2bf(v.w);
        ushort4 hv = make_ushort4(h0, h1, h2, h3);
        ushort4 lv = make_ushort4(f2bf(v.x - bf2f(h0)), f2bf(v.y - bf2f(h1)),
                                  f2bf(v.z - bf2f(h2)), f2bf(v.w - bf2f(h3)));
        *(ushort4*)(Xhi + row * 136 + c4 * 4) = hv;
        *(ushort4*)(Xlo + row * 136 + c4 * 4) = lv;
    }
    __syncthreads();

    int wid = tid >> 6, lane = tid & 63;
    int quad = lane >> 4, l16 = lane & 15;
    int rowA = wid * 16 + l16;

    f32x4 acc[8];
#pragma unroll
    for (int t = 0; t < 8; ++t) acc[t] = (f32x4){0.f, 0.f, 0.f, 0.f};

    for (int kc = 0; kc < 4; ++kc) {
        bf16x8 Ah = *(const bf16x8*)(Xhi + rowA * 136 + kc * 32 + quad * 8);
        bf16x8 Al = *(const bf16x8*)(Xlo + rowA * 136 + kc * 32 + quad * 8);
#pragma unroll
        for (int nt = 0; nt < 8; ++nt) {
            bf16x8 Bh = *(const bf16x8*)(Bhi + (((size_t)(nt * 4 + kc)) * 64 + lane) * 8);
            bf16x8 Bl = *(const bf16x8*)(Blo + (((size_t)(nt * 4 + kc)) * 64 + lane) * 8);
            acc[nt] = __builtin_amdgcn_mfma_f32_16x16x32_bf16(Ah, Bh, acc[nt], 0, 0, 0);
            acc[nt] = __builtin_amdgcn_mfma_f32_16x16x32_bf16(Al, Bh, acc[nt], 0, 0, 0);
            acc[nt] = __builtin_amdgcn_mfma_f32_16x16x32_bf16(Ah, Bl, acc[nt], 0, 0, 0);
        }
    }
    __syncthreads();

    int rowD0 = wid * 16 + quad * 4;
#pragma unroll
    for (int nt = 0; nt < 8; ++nt)
#pragma unroll
        for (int r = 0; r < 4; ++r)
            Hs[(rowD0 + r) * 136 + nt * 16 + l16] = acc[nt][r];
    __syncthreads();

    const float4* Hs4 = (const float4*)Hs;
    float4* H4 = (float4*)Hout;
#pragma unroll
    for (int i = 0; i < 8; ++i) {
        int idx = i * 256 + tid;
        int row = idx >> 5, c4 = idx & 31;
        int grow = base + row;
        if (grow < n) H4[(size_t)grow * 32 + c4] = Hs4[row * 34 + c4];
    }

    int drow = tid >> 2, q = tid & 3;
    const float4* as4 = (const float4*)a_s;
    const float4* ad4 = (const float4*)a_d;
    float s = 0.f, d = 0.f;
#pragma unroll
    for (int j = 0; j < 8; ++j) {
        float4 v = Hs4[drow * 34 + q * 8 + j];
        float4 a = as4[q * 8 + j];
        float4 b = ad4[q * 8 + j];
        s += v.x * a.x + v.y * a.y + v.z * a.z + v.w * a.w;
        d += v.x * b.x + v.y * b.y + v.z * b.z + v.w * b.w;
    }
    s += __shfl_xor(s, 1, WAVE); s += __shfl_xor(s, 2, WAVE);
    d += __shfl_xor(d, 1, WAVE); d += __shfl_xor(d, 2, WAVE);
    if (q == 0 && base + drow < n) {
        as_[base + drow] = s;
        ad_[base + drow] = d;
    }
}

__device__ __forceinline__ float leaky02(float x) { return x > 0.f ? x : 0.2f * x; }

// ---------------- GAT aggregation: EXACT round-8 kernel (measured 58.0us x5 rounds) ----------------
// DO NOT append epilogues or params to this kernel: rounds 9/10 showed any
// trailing code (even exec-masked-off) perturbs codegen of the gather loop
// (58 -> 98/131us). Half-wave per edge: one float4 gather inst (1KB) serves
// two edges, one exp weights two edges.
__global__ __launch_bounds__(256) void gat_aggregate(const float* __restrict__ h,
                                                     const float* __restrict__ as_,
                                                     const float* __restrict__ ad_,
                                                     const int* __restrict__ csr_src,
                                                     const int* __restrict__ offs,
                                                     const float* __restrict__ bias,
                                                     float* __restrict__ out, int n, int act) {
    int node = blockIdx.x * 4 + (threadIdx.x >> 6);
    int lane = threadIdx.x & 63;
    if (node >= n) return;
    int beg = offs[node], end = offs[node + 1];
    float adn = ad_[node];
    int half = lane >> 5;
    int l = lane & 31;
    const float4* h4 = (const float4*)h;

    float w_self = __expf(leaky02(as_[node] + adn));
    float4 acc;
    float sacc;
    {
        float ws = (half == 0) ? w_self : 0.f;
        float4 v = h4[(size_t)node * 32 + l];
        acc.x = ws * v.x; acc.y = ws * v.y; acc.z = ws * v.z; acc.w = ws * v.w;
        sacc = (lane == 0) ? w_self : 0.f;
    }
#pragma unroll 4
    for (int j = beg; j < end; j += 2) {
        int j0 = j + half;
        bool valid = j0 < end;
        int s = valid ? csr_src[j0] : node;
        float w = valid ? __expf(leaky02(as_[s] + adn)) : 0.f;
        float4 v = h4[(size_t)s * 32 + l];
        acc.x = fmaf(w, v.x, acc.x);
        acc.y = fmaf(w, v.y, acc.y);
        acc.z = fmaf(w, v.z, acc.z);
        acc.w = fmaf(w, v.w, acc.w);
        sacc += (l == 0) ? w : 0.f;
    }
    acc.x += __shfl_xor(acc.x, 32, WAVE);
    acc.y += __shfl_xor(acc.y, 32, WAVE);
    acc.z += __shfl_xor(acc.z, 32, WAVE);
    acc.w += __shfl_xor(acc.w, 32, WAVE);
    sacc += __shfl_xor(sacc, 32, WAVE);
    float stot = __shfl(sacc, 0, WAVE);
    float inv_s = 1.f / stot;
    if (half == 0) {
        float4 b = ((const float4*)bias)[l];
        float4 o;
        o.x = fmaf(acc.x, inv_s, b.x);
        o.y = fmaf(acc.y, inv_s, b.y);
        o.z = fmaf(acc.z, inv_s, b.z);
        o.w = fmaf(acc.w, inv_s, b.w);
        if (act == 1) {
            o.x = o.x > 0.f ? o.x : expm1f(o.x);
            o.y = o.y > 0.f ? o.y : expm1f(o.y);
            o.z = o.z > 0.f ? o.z : expm1f(o.z);
            o.w = o.w > 0.f ? o.w : expm1f(o.w);
        }
        ((float4*)(out + (size_t)node * 128))[l] = o;
    }
}

// ---------------- fused energy + segment softmax-pool + classifier ----------------
// Phase 0 computes energy for THIS block's own contiguous node range (the
// segment), replacing the standalone energy kernel (3 prior versions all
// latency-bound: tile ~63us, wave ~93us, mfma ~50us vs ~5us roofline).
// Here: thread (rg=node, quad=HP col) runs one 128-FMA chain; 256 parallel
// chains/block x many blocks/CU -> issue-bound ~5us aggregate. fp32 exact.
// energy staged through global (segment size unbounded -> can't use LDS);
// same-block write->syncthreads->read is same-XCD L2-coherent.
__global__ __launch_bounds__(256) void seg_pool_classify(const float* __restrict__ X,
                                                         float* __restrict__ energy,
                                                         const int* __restrict__ node_pos,
                                                         const float* __restrict__ Wp1,
                                                         const float* __restrict__ bp1,
                                                         const float* __restrict__ Wp2,
                                                         const float* __restrict__ bp2,
                                                         const float* __restrict__ Wl,
                                                         const float* __restrict__ bl,
                                                         float* __restrict__ out, int C, int HP) {
    int g = blockIdx.x;
    int beg = node_pos[g], end = node_pos[g + 1];
    int tid = threadIdx.x;
    __shared__ float sred[256];
    __shared__ float4 red[256];
    __shared__ float pP[128];

    int quad = tid & 31;
    int rg = tid >> 5;
    const float4* X4 = (const float4*)X;

    // ---- phase 0: energy for nodes [beg,end) ----
    {
        float b2 = bp2[0];
        for (int i = beg + rg; i < end; i += 8) {
            float v = 0.f;
            if (quad < HP) {
                const float4* xr4 = X4 + (size_t)i * 32;
                float a = 0.f;
#pragma unroll 8
                for (int k4 = 0; k4 < 32; ++k4) {
                    float4 xv = xr4[k4];   // broadcast across the 32 quad lanes
                    a = fmaf(xv.x, Wp1[(k4 * 4 + 0) * HP + quad],
                        fmaf(xv.y, Wp1[(k4 * 4 + 1) * HP + quad],
                        fmaf(xv.z, Wp1[(k4 * 4 + 2) * HP + quad],
                        fmaf(xv.w, Wp1[(k4 * 4 + 3) * HP + quad], a))));
                }
                a += bp1[quad];
                a = a > 0.f ? a : 0.f;
                v = a * Wp2[quad];
            }
#pragma unroll
            for (int o = 16; o > 0; o >>= 1) v += __shfl_xor(v, o, WAVE);  // within 32-lane half
            if (quad == 0) energy[i] = v + b2;
        }
    }
    __syncthreads();

    // ---- phase 1: softmax stats ----
    float m = -INFINITY;
    for (int i = beg + tid; i < end; i += 256) m = fmaxf(m, energy[i]);
    sred[tid] = m;
    __syncthreads();
    for (int o = 128; o > 0; o >>= 1) {
        if (tid < o) sred[tid] = fmaxf(sred[tid], sred[tid + o]);
        __syncthreads();
    }
    m = sred[0];
    __syncthreads();
    float s = 0.f;
    for (int i = beg + tid; i < end; i += 256) s += __expf(energy[i] - m);
    sred[tid] = s;
    __syncthreads();
    for (int o = 128; o > 0; o >>= 1) {
        if (tid < o) sred[tid] += sred[tid + o];
        __syncthreads();
    }
    s = sred[0];
    __syncthreads();
    float inv = (end > beg && s > 0.f) ? 1.f / s : 0.f;

    // ---- phase 2: weighted row sum (8 rows in flight) ----
    float4 acc = make_float4(0.f, 0.f, 0.f, 0.f);
    for (int i = beg + rg; i < end; i += 8) {
        float w = __expf(energy[i] - m) * inv;
        float4 v = X4[(size_t)i * 32 + quad];
        acc.x = fmaf(w, v.x, acc.x);
        acc.y = fmaf(w, v.y, acc.y);
        acc.z = fmaf(w, v.z, acc.z);
        acc.w = fmaf(w, v.w, acc.w);
    }
    red[tid] = acc;
    __syncthreads();
    if (rg < 4) {
        float4 o = red[tid + 128];
        acc.x += o.x; acc.y += o.y; acc.z += o.z; acc.w += o.w;
        red[tid] = acc;
    }
    __syncthreads();
    if (rg < 2) {
        float4 o = red[tid + 64];
        acc.x += o.x; acc.y += o.y; acc.z += o.z; acc.w += o.w;
        red[tid] = acc;
    }
    __syncthreads();
    if (rg == 0) {
        float4 o = red[tid + 32];
        acc.x += o.x; acc.y += o.y; acc.z += o.z; acc.w += o.w;
        pP[4 * quad + 0] = acc.x;
        pP[4 * quad + 1] = acc.y;
        pP[4 * quad + 2] = acc.z;
        pP[4 * quad + 3] = acc.w;
    }
    __syncthreads();

    // ---- phase 3: classifier row ----
    for (int c = tid; c < C; c += 256) {
        float a = bl[c];
#pragma unroll 8
        for (int k = 0; k < 128; ++k) a = fmaf(pP[k], Wl[(size_t)k * C + c], a);
        out[(size_t)g * C + c] = a;
    }
}

extern "C" void kernel_launch(void* const* d_in, const int* in_sizes, int n_in,
                              void* d_out, int out_size, void* d_ws, size_t ws_size,
                              hipStream_t stream) {
    const float* cfg_nodes = (const float*)d_in[0];
    const int* rel = (const int*)d_in[1];
    const int* node_pos = (const int*)d_in[2];
    const float* W_g1 = (const float*)d_in[3];
    const float* att_src1 = (const float*)d_in[4];
    const float* att_dst1 = (const float*)d_in[5];
    const float* b_g1 = (const float*)d_in[6];
    const float* W_g2 = (const float*)d_in[7];
    const float* att_src2 = (const float*)d_in[8];
    const float* att_dst2 = (const float*)d_in[9];
    const float* b_g2 = (const float*)d_in[10];
    const float* Wp1 = (const float*)d_in[11];
    const float* bp1 = (const float*)d_in[12];
    const float* Wp2 = (const float*)d_in[13];
    const float* bp2 = (const float*)d_in[14];
    const float* Wl = (const float*)d_in[15];
    const float* bl = (const float*)d_in[16];

    const int N = in_sizes[0] / 128;
    const int E = in_sizes[1] / 2;
    const int G = in_sizes[2] - 1;
    const int HP = in_sizes[12];
    const int C = out_size / G;

    const int* srcArr = rel;
    const int* dstArr = rel + E;

    char* w = (char*)d_ws;
    auto carve = [&](size_t bytes) -> char* {
        char* p = w;
        w += (bytes + 255) & ~(size_t)255;
        return p;
    };
    float* bufA = (float*)carve((size_t)N * 128 * 4);
    float* bufB = (float*)carve((size_t)N * 128 * 4);
    float* asv = (float*)carve((size_t)N * 4);
    float* adv = (float*)carve((size_t)N * 4);
    float* energy = (float*)carve((size_t)N * 4);
    int* deg = (int*)carve((size_t)N * 4);
    int* offs = (int*)carve((size_t)(N + 1) * 4);
    int* cursor = (int*)carve((size_t)N * 4);
    int* csr_src = (int*)carve((size_t)E * 4);
    int* bsums = (int*)carve(1024);
    unsigned short* W1hi = (unsigned short*)carve(16384 * 2);
    unsigned short* W1lo = (unsigned short*)carve(16384 * 2);
    unsigned short* W2hi = (unsigned short*)carve(16384 * 2);
    unsigned short* W2lo = (unsigned short*)carve(16384 * 2);

    const int nbN = (N + 255) / 256;
    const int nbC = ((E + 1) / 2 + 255) / 256;   // 2 edges per thread
    const int nbT = (N + GR - 1) / GR;

    // ---- CSR build + W pack ----
    hipMemsetAsync(deg, 0, (size_t)N * 4, stream);
    count_pack<<<nbC + 128, 256, 0, stream>>>(dstArr, deg, E, nbC,
                                              W_g1, W_g2, W1hi, W1lo, W2hi, W2lo);
    scan_block<<<nbN, 256, 0, stream>>>(deg, offs, bsums, N);
    scan_finish<<<nbN, 256, 0, stream>>>(offs, bsums, offs, cursor, N, E);
    scatter_edges<<<nbC, 256, 0, stream>>>(srcArr, dstArr, cursor, csr_src, E);

    // ---- GAT layer 1 ----
    gemm_mfma<<<nbT, 256, 0, stream>>>(cfg_nodes, W1hi, W1lo, att_src1, att_dst1,
                                       bufA, asv, adv, N);
    gat_aggregate<<<(N + 3) / 4, 256, 0, stream>>>(bufA, asv, adv, csr_src, offs, b_g1, bufB, N, 1);

    // ---- GAT layer 2 ----
    gemm_mfma<<<nbT, 256, 0, stream>>>(bufB, W2hi, W2lo, att_src2, att_dst2,
                                       bufA, asv, adv, N);
    gat_aggregate<<<(N + 3) / 4, 256, 0, stream>>>(bufA, asv, adv, csr_src, offs, b_g2, bufB, N, 0);

    // ---- energy + pooling + classifier (all fused) ----
    seg_pool_classify<<<G, 256, 0, stream>>>(bufB, energy, node_pos,
                                             Wp1, bp1, Wp2, bp2, Wl, bl,
                                             (float*)d_out, C, HP);
}

// Round 14
// 355.614 us; speedup vs baseline: 2.2292x; 2.2292x over previous
//
#include <hip/hip_runtime.h>
#include <hip/hip_bf16.h>
#include <math.h>

#define WAVE 64
#define GR 32   // rows per GEMM tile block (r14: 64->32 for 2x blocks/CU)

typedef __attribute__((ext_vector_type(8))) short bf16x8;
typedef __attribute__((ext_vector_type(4))) float f32x4;

// round-to-nearest-even fp32 -> bf16
__device__ __forceinline__ unsigned short f2bf(float x) {
    unsigned int b = __float_as_uint(x);
    unsigned int r = b + 0x7FFFu + ((b >> 16) & 1u);
    return (unsigned short)(r >> 16);
}
__device__ __forceinline__ float bf2f(unsigned short h) {
    return __uint_as_float(((unsigned int)h) << 16);
}

// ---------------- CSR build: count (2 edges/thread) + W-pack + Wp1-pack fused ----------------
__global__ void count_pack(const int* __restrict__ dst, int* __restrict__ deg, int E, int nbC,
                           const float* __restrict__ W1, const float* __restrict__ W2,
                           unsigned short* __restrict__ W1hi, unsigned short* __restrict__ W1lo,
                           unsigned short* __restrict__ W2hi, unsigned short* __restrict__ W2lo,
                           const float* __restrict__ Wp1, int HP,
                           unsigned short* __restrict__ Phi, unsigned short* __restrict__ Plo) {
    int b = blockIdx.x;
    if (b < nbC) {
        int e = (b * 256 + threadIdx.x) * 2;
        if (e + 1 < E) {
            int2 d = *(const int2*)(dst + e);
            atomicAdd(&deg[d.x], 1);
            atomicAdd(&deg[d.y], 1);
        } else if (e < E) {
            atomicAdd(&deg[dst[e]], 1);
        }
    } else if (b < nbC + 128) {
        int pb = b - nbC;   // 0..127: first 64 -> W1, next 64 -> W2
        const float* W = (pb >= 64) ? W2 : W1;
        unsigned short* Hi = (pb >= 64) ? W2hi : W1hi;
        unsigned short* Lo = (pb >= 64) ? W2lo : W1lo;
        int idx = (pb & 63) * 256 + threadIdx.x;   // 0..16383
        int j = idx & 7;
        int lane = (idx >> 3) & 63;
        int kc = (idx >> 9) & 3;
        int nt = idx >> 11;
        int k = kc * 32 + (lane >> 4) * 8 + j;
        int ncol = nt * 16 + (lane & 15);
        float x = W[k * 128 + ncol];
        unsigned short h = f2bf(x);
        Hi[idx] = h;
        Lo[idx] = f2bf(x - bf2f(h));
    } else {
        int idx = (b - nbC - 128) * 256 + threadIdx.x;   // 0..4095
        int j = idx & 7;
        int lane = (idx >> 3) & 63;
        int kc = (idx >> 9) & 3;
        int nt = idx >> 11;                               // 0..1
        int k = kc * 32 + (lane >> 4) * 8 + j;
        int ncol = nt * 16 + (lane & 15);
        float x = (ncol < HP) ? Wp1[k * HP + ncol] : 0.f;
        unsigned short h = f2bf(x);
        Phi[idx] = h;
        Plo[idx] = f2bf(x - bf2f(h));
    }
}

__global__ void scan_block(const int* __restrict__ in, int* __restrict__ part,
                           int* __restrict__ bsums, int n) {
    __shared__ int tmp[256];
    int tid = threadIdx.x;
    int i = blockIdx.x * 256 + tid;
    int v = (i < n) ? in[i] : 0;
    tmp[tid] = v;
    __syncthreads();
    for (int o = 1; o < 256; o <<= 1) {
        int t = (tid >= o) ? tmp[tid - o] : 0;
        __syncthreads();
        tmp[tid] += t;
        __syncthreads();
    }
    if (i < n) part[i] = tmp[tid] - v;
    if (tid == 255) bsums[blockIdx.x] = tmp[255];
}

__global__ void scan_finish(const int* __restrict__ part, const int* __restrict__ bsums,
                            int* __restrict__ offs, int* __restrict__ cursor,
                            int n, int Etot) {
    __shared__ int acc[256];
    int b = blockIdx.x, tid = threadIdx.x;
    int s = 0;
    for (int i = tid; i < b; i += 256) s += bsums[i];
    acc[tid] = s;
    __syncthreads();
    for (int o = 128; o > 0; o >>= 1) {
        if (tid < o) acc[tid] += acc[tid + o];
        __syncthreads();
    }
    int prefix = acc[0];
    int i = b * 256 + tid;
    if (i < n) {
        int v = part[i] + prefix;
        offs[i] = v;
        cursor[i] = v;
    }
    if (b == 0 && tid == 0) offs[n] = Etot;
}

__global__ void scatter_edges(const int* __restrict__ src, const int* __restrict__ dst,
                              int* __restrict__ cursor, int* __restrict__ csr_src, int E) {
    int e = (blockIdx.x * 256 + threadIdx.x) * 2;
    if (e + 1 < E) {
        int2 d = *(const int2*)(dst + e);
        int2 s = *(const int2*)(src + e);
        int p0 = atomicAdd(&cursor[d.x], 1);
        csr_src[p0] = s.x;
        int p1 = atomicAdd(&cursor[d.y], 1);
        csr_src[p1] = s.y;
    } else if (e < E) {
        int p = atomicAdd(&cursor[dst[e]], 1);
        csr_src[p] = src[e];
    }
}

// ---------------- MFMA GEMM (bf16x3 split) + attention dots, GR=32 ----------------
// r14: 32 rows/block -> LDS 17408 B -> 8 blocks/CU (r12 GR=64 was LDS-capped at
// 4 blocks/CU = 50% occupancy; cross-round algebra put each gemm at ~45-50us vs
// ~12us floor -> latency-bound). Wave wid: rows (wid&1)*16..+15, nt tiles
// (wid>>1)*4..+3 -> 48 MFMAs/wave. Same arithmetic/order as r12 -> same absmax.
__global__ __launch_bounds__(256) void gemm_mfma(const float* __restrict__ X,
                                                 const unsigned short* __restrict__ Bhi,
                                                 const unsigned short* __restrict__ Blo,
                                                 const float* __restrict__ a_s,
                                                 const float* __restrict__ a_d,
                                                 float* __restrict__ Hout,
                                                 float* __restrict__ as_,
                                                 float* __restrict__ ad_, int n) {
    __shared__ char lds[GR * 136 * 4];   // 17408 B: Xhi+Xlo (bf16), reused as Hs (fp32)
    unsigned short* Xhi = (unsigned short*)lds;
    unsigned short* Xlo = Xhi + GR * 136;
    float* Hs = (float*)lds;

    int tid = threadIdx.x;
    int base = blockIdx.x * GR;
    const float4* X4 = (const float4*)X;

#pragma unroll
    for (int i = 0; i < 4; ++i) {
        int idx = i * 256 + tid;
        int row = idx >> 5, c4 = idx & 31;
        int rs = base + row; if (rs >= n) rs = n - 1;
        float4 v = X4[(size_t)rs * 32 + c4];
        unsigned short h0 = f2bf(v.x), h1 = f2bf(v.y), h2 = f2bf(v.z), h3 = f2bf(v.w);
        ushort4 hv = make_ushort4(h0, h1, h2, h3);
        ushort4 lv = make_ushort4(f2bf(v.x - bf2f(h0)), f2bf(v.y - bf2f(h1)),
                                  f2bf(v.z - bf2f(h2)), f2bf(v.w - bf2f(h3)));
        *(ushort4*)(Xhi + row * 136 + c4 * 4) = hv;
        *(ushort4*)(Xlo + row * 136 + c4 * 4) = lv;
    }
    __syncthreads();

    int wid = tid >> 6, lane = tid & 63;
    int quad = lane >> 4, l16 = lane & 15;
    int rowA = (wid & 1) * 16 + l16;
    int ntb = (wid >> 1) * 4;

    f32x4 acc[4];
#pragma unroll
    for (int t = 0; t < 4; ++t) acc[t] = (f32x4){0.f, 0.f, 0.f, 0.f};

    for (int kc = 0; kc < 4; ++kc) {
        bf16x8 Ah = *(const bf16x8*)(Xhi + rowA * 136 + kc * 32 + quad * 8);
        bf16x8 Al = *(const bf16x8*)(Xlo + rowA * 136 + kc * 32 + quad * 8);
#pragma unroll
        for (int nt = 0; nt < 4; ++nt) {
            bf16x8 Bh = *(const bf16x8*)(Bhi + (((size_t)((ntb + nt) * 4 + kc)) * 64 + lane) * 8);
            bf16x8 Bl = *(const bf16x8*)(Blo + (((size_t)((ntb + nt) * 4 + kc)) * 64 + lane) * 8);
            acc[nt] = __builtin_amdgcn_mfma_f32_16x16x32_bf16(Ah, Bh, acc[nt], 0, 0, 0);
            acc[nt] = __builtin_amdgcn_mfma_f32_16x16x32_bf16(Al, Bh, acc[nt], 0, 0, 0);
            acc[nt] = __builtin_amdgcn_mfma_f32_16x16x32_bf16(Ah, Bl, acc[nt], 0, 0, 0);
        }
    }
    __syncthreads();

    int rowD0 = (wid & 1) * 16 + quad * 4;
#pragma unroll
    for (int nt = 0; nt < 4; ++nt)
#pragma unroll
        for (int r = 0; r < 4; ++r)
            Hs[(rowD0 + r) * 136 + (ntb + nt) * 16 + l16] = acc[nt][r];
    __syncthreads();

    const float4* Hs4 = (const float4*)Hs;
    float4* H4 = (float4*)Hout;
#pragma unroll
    for (int i = 0; i < 4; ++i) {
        int idx = i * 256 + tid;
        int row = idx >> 5, c4 = idx & 31;
        int grow = base + row;
        if (grow < n) H4[(size_t)grow * 32 + c4] = Hs4[row * 34 + c4];
    }

    // dots: thread -> row tid>>3, eighth tid&7 (16 elems), reduce over 8 lanes
    int drow = tid >> 3, q = tid & 7;
    const float4* as4 = (const float4*)a_s;
    const float4* ad4 = (const float4*)a_d;
    float s = 0.f, d = 0.f;
#pragma unroll
    for (int j = 0; j < 4; ++j) {
        float4 v = Hs4[drow * 34 + q * 4 + j];
        float4 a = as4[q * 4 + j];
        float4 b = ad4[q * 4 + j];
        s += v.x * a.x + v.y * a.y + v.z * a.z + v.w * a.w;
        d += v.x * b.x + v.y * b.y + v.z * b.z + v.w * b.w;
    }
    s += __shfl_xor(s, 1, WAVE); s += __shfl_xor(s, 2, WAVE); s += __shfl_xor(s, 4, WAVE);
    d += __shfl_xor(d, 1, WAVE); d += __shfl_xor(d, 2, WAVE); d += __shfl_xor(d, 4, WAVE);
    if (q == 0 && base + drow < n) {
        as_[base + drow] = s;
        ad_[base + drow] = d;
    }
}

__device__ __forceinline__ float leaky02(float x) { return x > 0.f ? x : 0.2f * x; }

// ---------------- GAT aggregation: EXACT round-8 kernel (measured 58.0us x6 rounds) ----------------
// DO NOT append epilogues or params to this kernel: rounds 9/10 showed any
// trailing code (even exec-masked-off) perturbs codegen of the gather loop
// (58 -> 98/131us). Half-wave per edge: one float4 gather inst (1KB) serves
// two edges, one exp weights two edges.
__global__ __launch_bounds__(256) void gat_aggregate(const float* __restrict__ h,
                                                     const float* __restrict__ as_,
                                                     const float* __restrict__ ad_,
                                                     const int* __restrict__ csr_src,
                                                     const int* __restrict__ offs,
                                                     const float* __restrict__ bias,
                                                     float* __restrict__ out, int n, int act) {
    int node = blockIdx.x * 4 + (threadIdx.x >> 6);
    int lane = threadIdx.x & 63;
    if (node >= n) return;
    int beg = offs[node], end = offs[node + 1];
    float adn = ad_[node];
    int half = lane >> 5;
    int l = lane & 31;
    const float4* h4 = (const float4*)h;

    float w_self = __expf(leaky02(as_[node] + adn));
    float4 acc;
    float sacc;
    {
        float ws = (half == 0) ? w_self : 0.f;
        float4 v = h4[(size_t)node * 32 + l];
        acc.x = ws * v.x; acc.y = ws * v.y; acc.z = ws * v.z; acc.w = ws * v.w;
        sacc = (lane == 0) ? w_self : 0.f;
    }
#pragma unroll 4
    for (int j = beg; j < end; j += 2) {
        int j0 = j + half;
        bool valid = j0 < end;
        int s = valid ? csr_src[j0] : node;
        float w = valid ? __expf(leaky02(as_[s] + adn)) : 0.f;
        float4 v = h4[(size_t)s * 32 + l];
        acc.x = fmaf(w, v.x, acc.x);
        acc.y = fmaf(w, v.y, acc.y);
        acc.z = fmaf(w, v.z, acc.z);
        acc.w = fmaf(w, v.w, acc.w);
        sacc += (l == 0) ? w : 0.f;
    }
    acc.x += __shfl_xor(acc.x, 32, WAVE);
    acc.y += __shfl_xor(acc.y, 32, WAVE);
    acc.z += __shfl_xor(acc.z, 32, WAVE);
    acc.w += __shfl_xor(acc.w, 32, WAVE);
    sacc += __shfl_xor(sacc, 32, WAVE);
    float stot = __shfl(sacc, 0, WAVE);
    float inv_s = 1.f / stot;
    if (half == 0) {
        float4 b = ((const float4*)bias)[l];
        float4 o;
        o.x = fmaf(acc.x, inv_s, b.x);
        o.y = fmaf(acc.y, inv_s, b.y);
        o.z = fmaf(acc.z, inv_s, b.z);
        o.w = fmaf(acc.w, inv_s, b.w);
        if (act == 1) {
            o.x = o.x > 0.f ? o.x : expm1f(o.x);
            o.y = o.y > 0.f ? o.y : expm1f(o.y);
            o.z = o.z > 0.f ? o.z : expm1f(o.z);
            o.w = o.w > 0.f ? o.w : expm1f(o.w);
        }
        ((float4*)(out + (size_t)node * 128))[l] = o;
    }
}

// ---------------- energy via MFMA, GR=32 ----------------
// Staging uses all 4 waves; waves 0,1 own 16 rows each and both nt tiles
// (12 MFMAs/wave); waves 2,3 exit after the barrier (MFMA phase is ~10% of
// the kernel; occupancy doubling is the win).
__global__ __launch_bounds__(256) void energy_mfma(const float* __restrict__ X,
                                                   const unsigned short* __restrict__ Phi,
                                                   const unsigned short* __restrict__ Plo,
                                                   const float* __restrict__ bp1,
                                                   const float* __restrict__ Wp2,
                                                   const float* __restrict__ bp2,
                                                   float* __restrict__ energy, int n, int HP) {
    __shared__ char lds[GR * 136 * 4];   // 17408 B
    unsigned short* Xhi = (unsigned short*)lds;
    unsigned short* Xlo = Xhi + GR * 136;
    int tid = threadIdx.x;
    int base = blockIdx.x * GR;
    const float4* X4 = (const float4*)X;
#pragma unroll
    for (int i = 0; i < 4; ++i) {
        int idx = i * 256 + tid;
        int row = idx >> 5, c4 = idx & 31;
        int rs = base + row; if (rs >= n) rs = n - 1;
        float4 v = X4[(size_t)rs * 32 + c4];
        unsigned short h0 = f2bf(v.x), h1 = f2bf(v.y), h2 = f2bf(v.z), h3 = f2bf(v.w);
        ushort4 hv = make_ushort4(h0, h1, h2, h3);
        ushort4 lv = make_ushort4(f2bf(v.x - bf2f(h0)), f2bf(v.y - bf2f(h1)),
                                  f2bf(v.z - bf2f(h2)), f2bf(v.w - bf2f(h3)));
        *(ushort4*)(Xhi + row * 136 + c4 * 4) = hv;
        *(ushort4*)(Xlo + row * 136 + c4 * 4) = lv;
    }
    __syncthreads();

    int wid = tid >> 6, lane = tid & 63;
    if (wid >= 2) return;   // no further barriers; waves 2,3 done
    int quad = lane >> 4, l16 = lane & 15;
    int rowA = wid * 16 + l16;

    f32x4 acc0 = (f32x4){0.f, 0.f, 0.f, 0.f};
    f32x4 acc1 = (f32x4){0.f, 0.f, 0.f, 0.f};
    for (int kc = 0; kc < 4; ++kc) {
        bf16x8 Ah = *(const bf16x8*)(Xhi + rowA * 136 + kc * 32 + quad * 8);
        bf16x8 Al = *(const bf16x8*)(Xlo + rowA * 136 + kc * 32 + quad * 8);
        bf16x8 B0h = *(const bf16x8*)(Phi + (((size_t)kc) * 64 + lane) * 8);
        bf16x8 B0l = *(const bf16x8*)(Plo + (((size_t)kc) * 64 + lane) * 8);
        bf16x8 B1h = *(const bf16x8*)(Phi + (((size_t)(4 + kc)) * 64 + lane) * 8);
        bf16x8 B1l = *(const bf16x8*)(Plo + (((size_t)(4 + kc)) * 64 + lane) * 8);
        acc0 = __builtin_amdgcn_mfma_f32_16x16x32_bf16(Ah, B0h, acc0, 0, 0, 0);
        acc0 = __builtin_amdgcn_mfma_f32_16x16x32_bf16(Al, B0h, acc0, 0, 0, 0);
        acc0 = __builtin_amdgcn_mfma_f32_16x16x32_bf16(Ah, B0l, acc0, 0, 0, 0);
        acc1 = __builtin_amdgcn_mfma_f32_16x16x32_bf16(Ah, B1h, acc1, 0, 0, 0);
        acc1 = __builtin_amdgcn_mfma_f32_16x16x32_bf16(Al, B1h, acc1, 0, 0, 0);
        acc1 = __builtin_amdgcn_mfma_f32_16x16x32_bf16(Ah, B1l, acc1, 0, 0, 0);
    }

    // epilogue: lane holds cols {l16, 16+l16} of rows wid*16 + quad*4 + r
    float b0 = bp1[l16];
    float w0 = Wp2[l16];
    int c1 = 16 + l16;
    int c1c = c1 < HP ? c1 : HP - 1;
    float b1 = bp1[c1c];
    float w1 = (c1 < HP) ? Wp2[c1c] : 0.f;
    float bp2v = bp2[0];
#pragma unroll
    for (int r = 0; r < 4; ++r) {
        float h0 = acc0[r] + b0;
        h0 = h0 > 0.f ? h0 : 0.f;
        float h1 = acc1[r] + b1;
        h1 = h1 > 0.f ? h1 : 0.f;
        float v = h0 * w0 + h1 * w1;
        v += __shfl_xor(v, 1, WAVE);
        v += __shfl_xor(v, 2, WAVE);
        v += __shfl_xor(v, 4, WAVE);
        v += __shfl_xor(v, 8, WAVE);
        int row = base + wid * 16 + quad * 4 + r;
        if (l16 == 0 && row < n) energy[row] = v + bp2v;
    }
}

// ---------------- fused segment softmax-pool + classifier (r12, measured-good) ----------------
__global__ __launch_bounds__(256) void seg_pool_classify(const float* __restrict__ X,
                                                         const float* __restrict__ energy,
                                                         const int* __restrict__ node_pos,
                                                         const float* __restrict__ Wl,
                                                         const float* __restrict__ bl,
                                                         float* __restrict__ out, int C) {
    int g = blockIdx.x;
    int beg = node_pos[g], end = node_pos[g + 1];
    int tid = threadIdx.x;
    __shared__ float sred[256];
    __shared__ float4 red[256];
    __shared__ float pP[128];

    float m = -INFINITY;
    for (int i = beg + tid; i < end; i += 256) m = fmaxf(m, energy[i]);
    sred[tid] = m;
    __syncthreads();
    for (int o = 128; o > 0; o >>= 1) {
        if (tid < o) sred[tid] = fmaxf(sred[tid], sred[tid + o]);
        __syncthreads();
    }
    m = sred[0];
    __syncthreads();
    float s = 0.f;
    for (int i = beg + tid; i < end; i += 256) s += __expf(energy[i] - m);
    sred[tid] = s;
    __syncthreads();
    for (int o = 128; o > 0; o >>= 1) {
        if (tid < o) sred[tid] += sred[tid + o];
        __syncthreads();
    }
    s = sred[0];
    __syncthreads();
    float inv = (end > beg && s > 0.f) ? 1.f / s : 0.f;

    int quad = tid & 31;
    int rg = tid >> 5;
    const float4* X4 = (const float4*)X;
    float4 acc = make_float4(0.f, 0.f, 0.f, 0.f);
    for (int i = beg + rg; i < end; i += 8) {
        float w = __expf(energy[i] - m) * inv;
        float4 v = X4[(size_t)i * 32 + quad];
        acc.x = fmaf(w, v.x, acc.x);
        acc.y = fmaf(w, v.y, acc.y);
        acc.z = fmaf(w, v.z, acc.z);
        acc.w = fmaf(w, v.w, acc.w);
    }
    red[tid] = acc;
    __syncthreads();
    if (rg < 4) {
        float4 o = red[tid + 128];
        acc.x += o.x; acc.y += o.y; acc.z += o.z; acc.w += o.w;
        red[tid] = acc;
    }
    __syncthreads();
    if (rg < 2) {
        float4 o = red[tid + 64];
        acc.x += o.x; acc.y += o.y; acc.z += o.z; acc.w += o.w;
        red[tid] = acc;
    }
    __syncthreads();
    if (rg == 0) {
        float4 o = red[tid + 32];
        acc.x += o.x; acc.y += o.y; acc.z += o.z; acc.w += o.w;
        pP[4 * quad + 0] = acc.x;
        pP[4 * quad + 1] = acc.y;
        pP[4 * quad + 2] = acc.z;
        pP[4 * quad + 3] = acc.w;
    }
    __syncthreads();

    for (int c = tid; c < C; c += 256) {
        float a = bl[c];
#pragma unroll 8
        for (int k = 0; k < 128; ++k) a = fmaf(pP[k], Wl[(size_t)k * C + c], a);
        out[(size_t)g * C + c] = a;
    }
}

extern "C" void kernel_launch(void* const* d_in, const int* in_sizes, int n_in,
                              void* d_out, int out_size, void* d_ws, size_t ws_size,
                              hipStream_t stream) {
    const float* cfg_nodes = (const float*)d_in[0];
    const int* rel = (const int*)d_in[1];
    const int* node_pos = (const int*)d_in[2];
    const float* W_g1 = (const float*)d_in[3];
    const float* att_src1 = (const float*)d_in[4];
    const float* att_dst1 = (const float*)d_in[5];
    const float* b_g1 = (const float*)d_in[6];
    const float* W_g2 = (const float*)d_in[7];
    const float* att_src2 = (const float*)d_in[8];
    const float* att_dst2 = (const float*)d_in[9];
    const float* b_g2 = (const float*)d_in[10];
    const float* Wp1 = (const float*)d_in[11];
    const float* bp1 = (const float*)d_in[12];
    const float* Wp2 = (const float*)d_in[13];
    const float* bp2 = (const float*)d_in[14];
    const float* Wl = (const float*)d_in[15];
    const float* bl = (const float*)d_in[16];

    const int N = in_sizes[0] / 128;
    const int E = in_sizes[1] / 2;
    const int G = in_sizes[2] - 1;
    const int HP = in_sizes[12];
    const int C = out_size / G;

    const int* srcArr = rel;
    const int* dstArr = rel + E;

    char* w = (char*)d_ws;
    auto carve = [&](size_t bytes) -> char* {
        char* p = w;
        w += (bytes + 255) & ~(size_t)255;
        return p;
    };
    float* bufA = (float*)carve((size_t)N * 128 * 4);
    float* bufB = (float*)carve((size_t)N * 128 * 4);
    float* asv = (float*)carve((size_t)N * 4);
    float* adv = (float*)carve((size_t)N * 4);
    float* energy = (float*)carve((size_t)N * 4);
    int* deg = (int*)carve((size_t)N * 4);
    int* offs = (int*)carve((size_t)(N + 1) * 4);
    int* cursor = (int*)carve((size_t)N * 4);
    int* csr_src = (int*)carve((size_t)E * 4);
    int* bsums = (int*)carve(1024);
    unsigned short* W1hi = (unsigned short*)carve(16384 * 2);
    unsigned short* W1lo = (unsigned short*)carve(16384 * 2);
    unsigned short* W2hi = (unsigned short*)carve(16384 * 2);
    unsigned short* W2lo = (unsigned short*)carve(16384 * 2);
    unsigned short* Phi = (unsigned short*)carve(4096 * 2);
    unsigned short* Plo = (unsigned short*)carve(4096 * 2);

    const int nbN = (N + 255) / 256;
    const int nbC = ((E + 1) / 2 + 255) / 256;   // 2 edges per thread
    const int nbT = (N + GR - 1) / GR;           // GR=32 -> 1563 blocks

    // ---- CSR build + W/Wp1 pack ----
    hipMemsetAsync(deg, 0, (size_t)N * 4, stream);
    count_pack<<<nbC + 144, 256, 0, stream>>>(dstArr, deg, E, nbC,
                                              W_g1, W_g2, W1hi, W1lo, W2hi, W2lo,
                                              Wp1, HP, Phi, Plo);
    scan_block<<<nbN, 256, 0, stream>>>(deg, offs, bsums, N);
    scan_finish<<<nbN, 256, 0, stream>>>(offs, bsums, offs, cursor, N, E);
    scatter_edges<<<nbC, 256, 0, stream>>>(srcArr, dstArr, cursor, csr_src, E);

    // ---- GAT layer 1 ----
    gemm_mfma<<<nbT, 256, 0, stream>>>(cfg_nodes, W1hi, W1lo, att_src1, att_dst1,
                                       bufA, asv, adv, N);
    gat_aggregate<<<(N + 3) / 4, 256, 0, stream>>>(bufA, asv, adv, csr_src, offs, b_g1, bufB, N, 1);

    // ---- GAT layer 2 ----
    gemm_mfma<<<nbT, 256, 0, stream>>>(bufB, W2hi, W2lo, att_src2, att_dst2,
                                       bufA, asv, adv, N);
    gat_aggregate<<<(N + 3) / 4, 256, 0, stream>>>(bufA, asv, adv, csr_src, offs, b_g2, bufB, N, 0);

    // ---- energy (MFMA) + pooling + classifier ----
    energy_mfma<<<nbT, 256, 0, stream>>>(bufB, Phi, Plo, bp1, Wp2, bp2, energy, N, HP);
    seg_pool_classify<<<G, 256, 0, stream>>>(bufB, energy, node_pos, Wl, bl, (float*)d_out, C);
}

// Round 15
// 338.470 us; speedup vs baseline: 2.3421x; 1.0507x over previous
//
#include <hip/hip_runtime.h>
#include <hip/hip_bf16.h>
#include <math.h>

#define WAVE 64
#define GR 32   // rows per GEMM tile block

typedef __attribute__((ext_vector_type(8))) short bf16x8;
typedef __attribute__((ext_vector_type(4))) float f32x4;
typedef __attribute__((ext_vector_type(4))) _Float16 half4;

// round-to-nearest-even fp32 -> bf16
__device__ __forceinline__ unsigned short f2bf(float x) {
    unsigned int b = __float_as_uint(x);
    unsigned int r = b + 0x7FFFu + ((b >> 16) & 1u);
    return (unsigned short)(r >> 16);
}
__device__ __forceinline__ float bf2f(unsigned short h) {
    return __uint_as_float(((unsigned int)h) << 16);
}

// ---------------- CSR build: count (2 edges/thread) + W-pack + Wp1-pack fused ----------------
__global__ void count_pack(const int* __restrict__ dst, int* __restrict__ deg, int E, int nbC,
                           const float* __restrict__ W1, const float* __restrict__ W2,
                           unsigned short* __restrict__ W1hi, unsigned short* __restrict__ W1lo,
                           unsigned short* __restrict__ W2hi, unsigned short* __restrict__ W2lo,
                           const float* __restrict__ Wp1, int HP,
                           unsigned short* __restrict__ Phi, unsigned short* __restrict__ Plo) {
    int b = blockIdx.x;
    if (b < nbC) {
        int e = (b * 256 + threadIdx.x) * 2;
        if (e + 1 < E) {
            int2 d = *(const int2*)(dst + e);
            atomicAdd(&deg[d.x], 1);
            atomicAdd(&deg[d.y], 1);
        } else if (e < E) {
            atomicAdd(&deg[dst[e]], 1);
        }
    } else if (b < nbC + 128) {
        int pb = b - nbC;   // 0..127: first 64 -> W1, next 64 -> W2
        const float* W = (pb >= 64) ? W2 : W1;
        unsigned short* Hi = (pb >= 64) ? W2hi : W1hi;
        unsigned short* Lo = (pb >= 64) ? W2lo : W1lo;
        int idx = (pb & 63) * 256 + threadIdx.x;   // 0..16383
        int j = idx & 7;
        int lane = (idx >> 3) & 63;
        int kc = (idx >> 9) & 3;
        int nt = idx >> 11;
        int k = kc * 32 + (lane >> 4) * 8 + j;
        int ncol = nt * 16 + (lane & 15);
        float x = W[k * 128 + ncol];
        unsigned short h = f2bf(x);
        Hi[idx] = h;
        Lo[idx] = f2bf(x - bf2f(h));
    } else {
        int idx = (b - nbC - 128) * 256 + threadIdx.x;   // 0..4095
        int j = idx & 7;
        int lane = (idx >> 3) & 63;
        int kc = (idx >> 9) & 3;
        int nt = idx >> 11;                               // 0..1
        int k = kc * 32 + (lane >> 4) * 8 + j;
        int ncol = nt * 16 + (lane & 15);
        float x = (ncol < HP) ? Wp1[k * HP + ncol] : 0.f;
        unsigned short h = f2bf(x);
        Phi[idx] = h;
        Plo[idx] = f2bf(x - bf2f(h));
    }
}

__global__ void scan_block(const int* __restrict__ in, int* __restrict__ part,
                           int* __restrict__ bsums, int n) {
    __shared__ int tmp[256];
    int tid = threadIdx.x;
    int i = blockIdx.x * 256 + tid;
    int v = (i < n) ? in[i] : 0;
    tmp[tid] = v;
    __syncthreads();
    for (int o = 1; o < 256; o <<= 1) {
        int t = (tid >= o) ? tmp[tid - o] : 0;
        __syncthreads();
        tmp[tid] += t;
        __syncthreads();
    }
    if (i < n) part[i] = tmp[tid] - v;
    if (tid == 255) bsums[blockIdx.x] = tmp[255];
}

__global__ void scan_finish(const int* __restrict__ part, const int* __restrict__ bsums,
                            int* __restrict__ offs, int* __restrict__ cursor,
                            int n, int Etot) {
    __shared__ int acc[256];
    int b = blockIdx.x, tid = threadIdx.x;
    int s = 0;
    for (int i = tid; i < b; i += 256) s += bsums[i];
    acc[tid] = s;
    __syncthreads();
    for (int o = 128; o > 0; o >>= 1) {
        if (tid < o) acc[tid] += acc[tid + o];
        __syncthreads();
    }
    int prefix = acc[0];
    int i = b * 256 + tid;
    if (i < n) {
        int v = part[i] + prefix;
        offs[i] = v;
        cursor[i] = v;
    }
    if (b == 0 && tid == 0) offs[n] = Etot;
}

__global__ void scatter_edges(const int* __restrict__ src, const int* __restrict__ dst,
                              int* __restrict__ cursor, int* __restrict__ csr_src, int E) {
    int e = (blockIdx.x * 256 + threadIdx.x) * 2;
    if (e + 1 < E) {
        int2 d = *(const int2*)(dst + e);
        int2 s = *(const int2*)(src + e);
        int p0 = atomicAdd(&cursor[d.x], 1);
        csr_src[p0] = s.x;
        int p1 = atomicAdd(&cursor[d.y], 1);
        csr_src[p1] = s.y;
    } else if (e < E) {
        int p = atomicAdd(&cursor[dst[e]], 1);
        csr_src[p] = src[e];
    }
}

// ---------------- MFMA GEMM (bf16x3 split) + attention dots, GR=32, fp16 H out ----------------
// r15: H is consumed ONLY by gat_aggregate's alpha-weighted gather (as_/ad_ are
// computed here in fp32). Writing H as fp16 (RNE, 4.9e-4 rel) halves both this
// kernel's H-write (25.6->12.8 MB) and gat's gather traffic (333->167 MB logical).
__global__ __launch_bounds__(256) void gemm_mfma(const float* __restrict__ X,
                                                 const unsigned short* __restrict__ Bhi,
                                                 const unsigned short* __restrict__ Blo,
                                                 const float* __restrict__ a_s,
                                                 const float* __restrict__ a_d,
                                                 _Float16* __restrict__ Hout,
                                                 float* __restrict__ as_,
                                                 float* __restrict__ ad_, int n) {
    __shared__ char lds[GR * 136 * 4];   // 17408 B: Xhi+Xlo (bf16), reused as Hs (fp32)
    unsigned short* Xhi = (unsigned short*)lds;
    unsigned short* Xlo = Xhi + GR * 136;
    float* Hs = (float*)lds;

    int tid = threadIdx.x;
    int base = blockIdx.x * GR;
    const float4* X4 = (const float4*)X;

#pragma unroll
    for (int i = 0; i < 4; ++i) {
        int idx = i * 256 + tid;
        int row = idx >> 5, c4 = idx & 31;
        int rs = base + row; if (rs >= n) rs = n - 1;
        float4 v = X4[(size_t)rs * 32 + c4];
        unsigned short h0 = f2bf(v.x), h1 = f2bf(v.y), h2 = f2bf(v.z), h3 = f2bf(v.w);
        ushort4 hv = make_ushort4(h0, h1, h2, h3);
        ushort4 lv = make_ushort4(f2bf(v.x - bf2f(h0)), f2bf(v.y - bf2f(h1)),
                                  f2bf(v.z - bf2f(h2)), f2bf(v.w - bf2f(h3)));
        *(ushort4*)(Xhi + row * 136 + c4 * 4) = hv;
        *(ushort4*)(Xlo + row * 136 + c4 * 4) = lv;
    }
    __syncthreads();

    int wid = tid >> 6, lane = tid & 63;
    int quad = lane >> 4, l16 = lane & 15;
    int rowA = (wid & 1) * 16 + l16;
    int ntb = (wid >> 1) * 4;

    f32x4 acc[4];
#pragma unroll
    for (int t = 0; t < 4; ++t) acc[t] = (f32x4){0.f, 0.f, 0.f, 0.f};

    for (int kc = 0; kc < 4; ++kc) {
        bf16x8 Ah = *(const bf16x8*)(Xhi + rowA * 136 + kc * 32 + quad * 8);
        bf16x8 Al = *(const bf16x8*)(Xlo + rowA * 136 + kc * 32 + quad * 8);
#pragma unroll
        for (int nt = 0; nt < 4; ++nt) {
            bf16x8 Bh = *(const bf16x8*)(Bhi + (((size_t)((ntb + nt) * 4 + kc)) * 64 + lane) * 8);
            bf16x8 Bl = *(const bf16x8*)(Blo + (((size_t)((ntb + nt) * 4 + kc)) * 64 + lane) * 8);
            acc[nt] = __builtin_amdgcn_mfma_f32_16x16x32_bf16(Ah, Bh, acc[nt], 0, 0, 0);
            acc[nt] = __builtin_amdgcn_mfma_f32_16x16x32_bf16(Al, Bh, acc[nt], 0, 0, 0);
            acc[nt] = __builtin_amdgcn_mfma_f32_16x16x32_bf16(Ah, Bl, acc[nt], 0, 0, 0);
        }
    }
    __syncthreads();

    int rowD0 = (wid & 1) * 16 + quad * 4;
#pragma unroll
    for (int nt = 0; nt < 4; ++nt)
#pragma unroll
        for (int r = 0; r < 4; ++r)
            Hs[(rowD0 + r) * 136 + (ntb + nt) * 16 + l16] = acc[nt][r];
    __syncthreads();

    const float4* Hs4 = (const float4*)Hs;
    half4* H4 = (half4*)Hout;
#pragma unroll
    for (int i = 0; i < 4; ++i) {
        int idx = i * 256 + tid;
        int row = idx >> 5, c4 = idx & 31;
        int grow = base + row;
        if (grow < n) {
            float4 v = Hs4[row * 34 + c4];
            half4 hv = {(_Float16)v.x, (_Float16)v.y, (_Float16)v.z, (_Float16)v.w};
            H4[(size_t)grow * 32 + c4] = hv;   // 8B/lane coalesced
        }
    }

    // dots (fp32, from LDS): thread -> row tid>>3, eighth tid&7, reduce over 8 lanes
    int drow = tid >> 3, q = tid & 7;
    const float4* as4 = (const float4*)a_s;
    const float4* ad4 = (const float4*)a_d;
    float s = 0.f, d = 0.f;
#pragma unroll
    for (int j = 0; j < 4; ++j) {
        float4 v = Hs4[drow * 34 + q * 4 + j];
        float4 a = as4[q * 4 + j];
        float4 b = ad4[q * 4 + j];
        s += v.x * a.x + v.y * a.y + v.z * a.z + v.w * a.w;
        d += v.x * b.x + v.y * b.y + v.z * b.z + v.w * b.w;
    }
    s += __shfl_xor(s, 1, WAVE); s += __shfl_xor(s, 2, WAVE); s += __shfl_xor(s, 4, WAVE);
    d += __shfl_xor(d, 1, WAVE); d += __shfl_xor(d, 2, WAVE); d += __shfl_xor(d, 4, WAVE);
    if (q == 0 && base + drow < n) {
        as_[base + drow] = s;
        ad_[base + drow] = d;
    }
}

__device__ __forceinline__ float leaky02(float x) { return x > 0.f ? x : 0.2f * x; }

// ---------------- GAT aggregation: r8 loop shape, fp16 h gather ----------------
// Loop structure identical to the measured-58us r8 kernel (half-wave per edge;
// one gather inst serves two edges) — only the gather width changes:
// float4 (16B/lane) -> half4 (8B/lane). Accumulation fp32 (v_fma_mix).
// DO NOT append epilogues (r9/r10 codegen-poison lesson).
__global__ __launch_bounds__(256) void gat_aggregate(const _Float16* __restrict__ h,
                                                     const float* __restrict__ as_,
                                                     const float* __restrict__ ad_,
                                                     const int* __restrict__ csr_src,
                                                     const int* __restrict__ offs,
                                                     const float* __restrict__ bias,
                                                     float* __restrict__ out, int n, int act) {
    int node = blockIdx.x * 4 + (threadIdx.x >> 6);
    int lane = threadIdx.x & 63;
    if (node >= n) return;
    int beg = offs[node], end = offs[node + 1];
    float adn = ad_[node];
    int half = lane >> 5;
    int l = lane & 31;
    const half4* h4 = (const half4*)h;

    float w_self = __expf(leaky02(as_[node] + adn));
    float4 acc;
    float sacc;
    {
        float ws = (half == 0) ? w_self : 0.f;
        half4 v = h4[(size_t)node * 32 + l];
        acc.x = ws * (float)v.x; acc.y = ws * (float)v.y;
        acc.z = ws * (float)v.z; acc.w = ws * (float)v.w;
        sacc = (lane == 0) ? w_self : 0.f;
    }
#pragma unroll 4
    for (int j = beg; j < end; j += 2) {
        int j0 = j + half;
        bool valid = j0 < end;
        int s = valid ? csr_src[j0] : node;
        float w = valid ? __expf(leaky02(as_[s] + adn)) : 0.f;
        half4 v = h4[(size_t)s * 32 + l];
        acc.x = fmaf(w, (float)v.x, acc.x);
        acc.y = fmaf(w, (float)v.y, acc.y);
        acc.z = fmaf(w, (float)v.z, acc.z);
        acc.w = fmaf(w, (float)v.w, acc.w);
        sacc += (l == 0) ? w : 0.f;
    }
    acc.x += __shfl_xor(acc.x, 32, WAVE);
    acc.y += __shfl_xor(acc.y, 32, WAVE);
    acc.z += __shfl_xor(acc.z, 32, WAVE);
    acc.w += __shfl_xor(acc.w, 32, WAVE);
    sacc += __shfl_xor(sacc, 32, WAVE);
    float stot = __shfl(sacc, 0, WAVE);
    float inv_s = 1.f / stot;
    if (half == 0) {
        float4 b = ((const float4*)bias)[l];
        float4 o;
        o.x = fmaf(acc.x, inv_s, b.x);
        o.y = fmaf(acc.y, inv_s, b.y);
        o.z = fmaf(acc.z, inv_s, b.z);
        o.w = fmaf(acc.w, inv_s, b.w);
        if (act == 1) {
            o.x = o.x > 0.f ? o.x : expm1f(o.x);
            o.y = o.y > 0.f ? o.y : expm1f(o.y);
            o.z = o.z > 0.f ? o.z : expm1f(o.z);
            o.w = o.w > 0.f ? o.w : expm1f(o.w);
        }
        ((float4*)(out + (size_t)node * 128))[l] = o;
    }
}

// ---------------- energy via MFMA, GR=32 (r14, measured-good) ----------------
__global__ __launch_bounds__(256) void energy_mfma(const float* __restrict__ X,
                                                   const unsigned short* __restrict__ Phi,
                                                   const unsigned short* __restrict__ Plo,
                                                   const float* __restrict__ bp1,
                                                   const float* __restrict__ Wp2,
                                                   const float* __restrict__ bp2,
                                                   float* __restrict__ energy, int n, int HP) {
    __shared__ char lds[GR * 136 * 4];   // 17408 B
    unsigned short* Xhi = (unsigned short*)lds;
    unsigned short* Xlo = Xhi + GR * 136;
    int tid = threadIdx.x;
    int base = blockIdx.x * GR;
    const float4* X4 = (const float4*)X;
#pragma unroll
    for (int i = 0; i < 4; ++i) {
        int idx = i * 256 + tid;
        int row = idx >> 5, c4 = idx & 31;
        int rs = base + row; if (rs >= n) rs = n - 1;
        float4 v = X4[(size_t)rs * 32 + c4];
        unsigned short h0 = f2bf(v.x), h1 = f2bf(v.y), h2 = f2bf(v.z), h3 = f2bf(v.w);
        ushort4 hv = make_ushort4(h0, h1, h2, h3);
        ushort4 lv = make_ushort4(f2bf(v.x - bf2f(h0)), f2bf(v.y - bf2f(h1)),
                                  f2bf(v.z - bf2f(h2)), f2bf(v.w - bf2f(h3)));
        *(ushort4*)(Xhi + row * 136 + c4 * 4) = hv;
        *(ushort4*)(Xlo + row * 136 + c4 * 4) = lv;
    }
    __syncthreads();

    int wid = tid >> 6, lane = tid & 63;
    if (wid >= 2) return;   // waves 2,3 done after staging
    int quad = lane >> 4, l16 = lane & 15;
    int rowA = wid * 16 + l16;

    f32x4 acc0 = (f32x4){0.f, 0.f, 0.f, 0.f};
    f32x4 acc1 = (f32x4){0.f, 0.f, 0.f, 0.f};
    for (int kc = 0; kc < 4; ++kc) {
        bf16x8 Ah = *(const bf16x8*)(Xhi + rowA * 136 + kc * 32 + quad * 8);
        bf16x8 Al = *(const bf16x8*)(Xlo + rowA * 136 + kc * 32 + quad * 8);
        bf16x8 B0h = *(const bf16x8*)(Phi + (((size_t)kc) * 64 + lane) * 8);
        bf16x8 B0l = *(const bf16x8*)(Plo + (((size_t)kc) * 64 + lane) * 8);
        bf16x8 B1h = *(const bf16x8*)(Phi + (((size_t)(4 + kc)) * 64 + lane) * 8);
        bf16x8 B1l = *(const bf16x8*)(Plo + (((size_t)(4 + kc)) * 64 + lane) * 8);
        acc0 = __builtin_amdgcn_mfma_f32_16x16x32_bf16(Ah, B0h, acc0, 0, 0, 0);
        acc0 = __builtin_amdgcn_mfma_f32_16x16x32_bf16(Al, B0h, acc0, 0, 0, 0);
        acc0 = __builtin_amdgcn_mfma_f32_16x16x32_bf16(Ah, B0l, acc0, 0, 0, 0);
        acc1 = __builtin_amdgcn_mfma_f32_16x16x32_bf16(Ah, B1h, acc1, 0, 0, 0);
        acc1 = __builtin_amdgcn_mfma_f32_16x16x32_bf16(Al, B1h, acc1, 0, 0, 0);
        acc1 = __builtin_amdgcn_mfma_f32_16x16x32_bf16(Ah, B1l, acc1, 0, 0, 0);
    }

    float b0 = bp1[l16];
    float w0 = Wp2[l16];
    int c1 = 16 + l16;
    int c1c = c1 < HP ? c1 : HP - 1;
    float b1 = bp1[c1c];
    float w1 = (c1 < HP) ? Wp2[c1c] : 0.f;
    float bp2v = bp2[0];
#pragma unroll
    for (int r = 0; r < 4; ++r) {
        float h0 = acc0[r] + b0;
        h0 = h0 > 0.f ? h0 : 0.f;
        float h1 = acc1[r] + b1;
        h1 = h1 > 0.f ? h1 : 0.f;
        float v = h0 * w0 + h1 * w1;
        v += __shfl_xor(v, 1, WAVE);
        v += __shfl_xor(v, 2, WAVE);
        v += __shfl_xor(v, 4, WAVE);
        v += __shfl_xor(v, 8, WAVE);
        int row = base + wid * 16 + quad * 4 + r;
        if (l16 == 0 && row < n) energy[row] = v + bp2v;
    }
}

// ---------------- fused segment softmax-pool + classifier (r12, measured-good) ----------------
__global__ __launch_bounds__(256) void seg_pool_classify(const float* __restrict__ X,
                                                         const float* __restrict__ energy,
                                                         const int* __restrict__ node_pos,
                                                         const float* __restrict__ Wl,
                                                         const float* __restrict__ bl,
                                                         float* __restrict__ out, int C) {
    int g = blockIdx.x;
    int beg = node_pos[g], end = node_pos[g + 1];
    int tid = threadIdx.x;
    __shared__ float sred[256];
    __shared__ float4 red[256];
    __shared__ float pP[128];

    float m = -INFINITY;
    for (int i = beg + tid; i < end; i += 256) m = fmaxf(m, energy[i]);
    sred[tid] = m;
    __syncthreads();
    for (int o = 128; o > 0; o >>= 1) {
        if (tid < o) sred[tid] = fmaxf(sred[tid], sred[tid + o]);
        __syncthreads();
    }
    m = sred[0];
    __syncthreads();
    float s = 0.f;
    for (int i = beg + tid; i < end; i += 256) s += __expf(energy[i] - m);
    sred[tid] = s;
    __syncthreads();
    for (int o = 128; o > 0; o >>= 1) {
        if (tid < o) sred[tid] += sred[tid + o];
        __syncthreads();
    }
    s = sred[0];
    __syncthreads();
    float inv = (end > beg && s > 0.f) ? 1.f / s : 0.f;

    int quad = tid & 31;
    int rg = tid >> 5;
    const float4* X4 = (const float4*)X;
    float4 acc = make_float4(0.f, 0.f, 0.f, 0.f);
    for (int i = beg + rg; i < end; i += 8) {
        float w = __expf(energy[i] - m) * inv;
        float4 v = X4[(size_t)i * 32 + quad];
        acc.x = fmaf(w, v.x, acc.x);
        acc.y = fmaf(w, v.y, acc.y);
        acc.z = fmaf(w, v.z, acc.z);
        acc.w = fmaf(w, v.w, acc.w);
    }
    red[tid] = acc;
    __syncthreads();
    if (rg < 4) {
        float4 o = red[tid + 128];
        acc.x += o.x; acc.y += o.y; acc.z += o.z; acc.w += o.w;
        red[tid] = acc;
    }
    __syncthreads();
    if (rg < 2) {
        float4 o = red[tid + 64];
        acc.x += o.x; acc.y += o.y; acc.z += o.z; acc.w += o.w;
        red[tid] = acc;
    }
    __syncthreads();
    if (rg == 0) {
        float4 o = red[tid + 32];
        acc.x += o.x; acc.y += o.y; acc.z += o.z; acc.w += o.w;
        pP[4 * quad + 0] = acc.x;
        pP[4 * quad + 1] = acc.y;
        pP[4 * quad + 2] = acc.z;
        pP[4 * quad + 3] = acc.w;
    }
    __syncthreads();

    for (int c = tid; c < C; c += 256) {
        float a = bl[c];
#pragma unroll 8
        for (int k = 0; k < 128; ++k) a = fmaf(pP[k], Wl[(size_t)k * C + c], a);
        out[(size_t)g * C + c] = a;
    }
}

extern "C" void kernel_launch(void* const* d_in, const int* in_sizes, int n_in,
                              void* d_out, int out_size, void* d_ws, size_t ws_size,
                              hipStream_t stream) {
    const float* cfg_nodes = (const float*)d_in[0];
    const int* rel = (const int*)d_in[1];
    const int* node_pos = (const int*)d_in[2];
    const float* W_g1 = (const float*)d_in[3];
    const float* att_src1 = (const float*)d_in[4];
    const float* att_dst1 = (const float*)d_in[5];
    const float* b_g1 = (const float*)d_in[6];
    const float* W_g2 = (const float*)d_in[7];
    const float* att_src2 = (const float*)d_in[8];
    const float* att_dst2 = (const float*)d_in[9];
    const float* b_g2 = (const float*)d_in[10];
    const float* Wp1 = (const float*)d_in[11];
    const float* bp1 = (const float*)d_in[12];
    const float* Wp2 = (const float*)d_in[13];
    const float* bp2 = (const float*)d_in[14];
    const float* Wl = (const float*)d_in[15];
    const float* bl = (const float*)d_in[16];

    const int N = in_sizes[0] / 128;
    const int E = in_sizes[1] / 2;
    const int G = in_sizes[2] - 1;
    const int HP = in_sizes[12];
    const int C = out_size / G;

    const int* srcArr = rel;
    const int* dstArr = rel + E;

    char* w = (char*)d_ws;
    auto carve = [&](size_t bytes) -> char* {
        char* p = w;
        w += (bytes + 255) & ~(size_t)255;
        return p;
    };
    _Float16* bufH = (_Float16*)carve((size_t)N * 128 * 2);   // fp16 gemm output (gat gather src)
    float* bufB = (float*)carve((size_t)N * 128 * 4);
    float* asv = (float*)carve((size_t)N * 4);
    float* adv = (float*)carve((size_t)N * 4);
    float* energy = (float*)carve((size_t)N * 4);
    int* deg = (int*)carve((size_t)N * 4);
    int* offs = (int*)carve((size_t)(N + 1) * 4);
    int* cursor = (int*)carve((size_t)N * 4);
    int* csr_src = (int*)carve((size_t)E * 4);
    int* bsums = (int*)carve(1024);
    unsigned short* W1hi = (unsigned short*)carve(16384 * 2);
    unsigned short* W1lo = (unsigned short*)carve(16384 * 2);
    unsigned short* W2hi = (unsigned short*)carve(16384 * 2);
    unsigned short* W2lo = (unsigned short*)carve(16384 * 2);
    unsigned short* Phi = (unsigned short*)carve(4096 * 2);
    unsigned short* Plo = (unsigned short*)carve(4096 * 2);

    const int nbN = (N + 255) / 256;
    const int nbC = ((E + 1) / 2 + 255) / 256;   // 2 edges per thread
    const int nbT = (N + GR - 1) / GR;           // GR=32 -> 1563 blocks

    // ---- CSR build + W/Wp1 pack ----
    hipMemsetAsync(deg, 0, (size_t)N * 4, stream);
    count_pack<<<nbC + 144, 256, 0, stream>>>(dstArr, deg, E, nbC,
                                              W_g1, W_g2, W1hi, W1lo, W2hi, W2lo,
                                              Wp1, HP, Phi, Plo);
    scan_block<<<nbN, 256, 0, stream>>>(deg, offs, bsums, N);
    scan_finish<<<nbN, 256, 0, stream>>>(offs, bsums, offs, cursor, N, E);
    scatter_edges<<<nbC, 256, 0, stream>>>(srcArr, dstArr, cursor, csr_src, E);

    // ---- GAT layer 1 ----
    gemm_mfma<<<nbT, 256, 0, stream>>>(cfg_nodes, W1hi, W1lo, att_src1, att_dst1,
                                       bufH, asv, adv, N);
    gat_aggregate<<<(N + 3) / 4, 256, 0, stream>>>(bufH, asv, adv, csr_src, offs, b_g1, bufB, N, 1);

    // ---- GAT layer 2 ----
    gemm_mfma<<<nbT, 256, 0, stream>>>(bufB, W2hi, W2lo, att_src2, att_dst2,
                                       bufH, asv, adv, N);
    gat_aggregate<<<(N + 3) / 4, 256, 0, stream>>>(bufH, asv, adv, csr_src, offs, b_g2, bufB, N, 0);

    // ---- energy (MFMA) + pooling + classifier ----
    energy_mfma<<<nbT, 256, 0, stream>>>(bufB, Phi, Plo, bp1, Wp2, bp2, energy, N, HP);
    seg_pool_classify<<<G, 256, 0, stream>>>(bufB, energy, node_pos, Wl, bl, (float*)d_out, C);
}

// Round 16
// 330.169 us; speedup vs baseline: 2.4010x; 1.0251x over previous
//
#include <hip/hip_runtime.h>
#include <hip/hip_bf16.h>
#include <math.h>

#define WAVE 64
#define GR 32   // rows per GEMM tile block

typedef __attribute__((ext_vector_type(8))) _Float16 half8;
typedef __attribute__((ext_vector_type(4))) float f32x4;
typedef __attribute__((ext_vector_type(4))) _Float16 half4;

// ---------------- CSR build: count (2 edges/thread) + W-pack (fp16) fused ----------------
// blocks [0,nbC): degree count; [nbC,nbC+128): W1/W2 fp16 B-fragment pack;
// [nbC+128,nbC+144): Wp1 fp16 B-fragment pack (25 cols padded to 32).
// r16: single fp16 fragments (was bf16 hi/lo x3-split); error budget has 4.6x
// headroom at r15's absmax 1.95e-3, fp16 gemm predicted ~4e-3 < 9.06e-3.
__global__ void count_pack(const int* __restrict__ dst, int* __restrict__ deg, int E, int nbC,
                           const float* __restrict__ W1, const float* __restrict__ W2,
                           _Float16* __restrict__ W1h, _Float16* __restrict__ W2h,
                           const float* __restrict__ Wp1, int HP,
                           _Float16* __restrict__ Ph) {
    int b = blockIdx.x;
    if (b < nbC) {
        int e = (b * 256 + threadIdx.x) * 2;
        if (e + 1 < E) {
            int2 d = *(const int2*)(dst + e);
            atomicAdd(&deg[d.x], 1);
            atomicAdd(&deg[d.y], 1);
        } else if (e < E) {
            atomicAdd(&deg[dst[e]], 1);
        }
    } else if (b < nbC + 128) {
        int pb = b - nbC;   // 0..127: first 64 -> W1, next 64 -> W2
        const float* W = (pb >= 64) ? W2 : W1;
        _Float16* Hf = (pb >= 64) ? W2h : W1h;
        int idx = (pb & 63) * 256 + threadIdx.x;   // 0..16383
        int j = idx & 7;
        int lane = (idx >> 3) & 63;
        int kc = (idx >> 9) & 3;
        int nt = idx >> 11;
        int k = kc * 32 + (lane >> 4) * 8 + j;
        int ncol = nt * 16 + (lane & 15);
        Hf[idx] = (_Float16)W[k * 128 + ncol];
    } else {
        int idx = (b - nbC - 128) * 256 + threadIdx.x;   // 0..4095
        int j = idx & 7;
        int lane = (idx >> 3) & 63;
        int kc = (idx >> 9) & 3;
        int nt = idx >> 11;                               // 0..1
        int k = kc * 32 + (lane >> 4) * 8 + j;
        int ncol = nt * 16 + (lane & 15);
        float x = (ncol < HP) ? Wp1[k * HP + ncol] : 0.f;
        Ph[idx] = (_Float16)x;
    }
}

__global__ void scan_block(const int* __restrict__ in, int* __restrict__ part,
                           int* __restrict__ bsums, int n) {
    __shared__ int tmp[256];
    int tid = threadIdx.x;
    int i = blockIdx.x * 256 + tid;
    int v = (i < n) ? in[i] : 0;
    tmp[tid] = v;
    __syncthreads();
    for (int o = 1; o < 256; o <<= 1) {
        int t = (tid >= o) ? tmp[tid - o] : 0;
        __syncthreads();
        tmp[tid] += t;
        __syncthreads();
    }
    if (i < n) part[i] = tmp[tid] - v;
    if (tid == 255) bsums[blockIdx.x] = tmp[255];
}

__global__ void scan_finish(const int* __restrict__ part, const int* __restrict__ bsums,
                            int* __restrict__ offs, int* __restrict__ cursor,
                            int n, int Etot) {
    __shared__ int acc[256];
    int b = blockIdx.x, tid = threadIdx.x;
    int s = 0;
    for (int i = tid; i < b; i += 256) s += bsums[i];
    acc[tid] = s;
    __syncthreads();
    for (int o = 128; o > 0; o >>= 1) {
        if (tid < o) acc[tid] += acc[tid + o];
        __syncthreads();
    }
    int prefix = acc[0];
    int i = b * 256 + tid;
    if (i < n) {
        int v = part[i] + prefix;
        offs[i] = v;
        cursor[i] = v;
    }
    if (b == 0 && tid == 0) offs[n] = Etot;
}

__global__ void scatter_edges(const int* __restrict__ src, const int* __restrict__ dst,
                              int* __restrict__ cursor, int* __restrict__ csr_src, int E) {
    int e = (blockIdx.x * 256 + threadIdx.x) * 2;
    if (e + 1 < E) {
        int2 d = *(const int2*)(dst + e);
        int2 s = *(const int2*)(src + e);
        int p0 = atomicAdd(&cursor[d.x], 1);
        csr_src[p0] = s.x;
        int p1 = atomicAdd(&cursor[d.y], 1);
        csr_src[p1] = s.y;
    } else if (e < E) {
        int p = atomicAdd(&cursor[dst[e]], 1);
        csr_src[p] = src[e];
    }
}

// ---------------- fp16 MFMA GEMM + attention dots, GR=32, fp16 H out ----------------
// r16: single f16 MFMA (was bf16x3). Staging halves (one fp16 tile, no hi/lo
// split), MFMA count 48->16 per wave. Dots stay fp32 from the fp32 Hs stage.
__global__ __launch_bounds__(256) void gemm_mfma(const float* __restrict__ X,
                                                 const _Float16* __restrict__ Bh,
                                                 const float* __restrict__ a_s,
                                                 const float* __restrict__ a_d,
                                                 _Float16* __restrict__ Hout,
                                                 float* __restrict__ as_,
                                                 float* __restrict__ ad_, int n) {
    __shared__ char lds[GR * 136 * 4];   // phase A: Xh fp16 (8704B); phase B: Hs fp32 (17408B)
    _Float16* Xh = (_Float16*)lds;
    float* Hs = (float*)lds;

    int tid = threadIdx.x;
    int base = blockIdx.x * GR;
    const float4* X4 = (const float4*)X;

#pragma unroll
    for (int i = 0; i < 4; ++i) {
        int idx = i * 256 + tid;
        int row = idx >> 5, c4 = idx & 31;
        int rs = base + row; if (rs >= n) rs = n - 1;
        float4 v = X4[(size_t)rs * 32 + c4];
        half4 hv = {(_Float16)v.x, (_Float16)v.y, (_Float16)v.z, (_Float16)v.w};
        *(half4*)(Xh + row * 136 + c4 * 4) = hv;
    }
    __syncthreads();

    int wid = tid >> 6, lane = tid & 63;
    int quad = lane >> 4, l16 = lane & 15;
    int rowA = (wid & 1) * 16 + l16;
    int ntb = (wid >> 1) * 4;

    f32x4 acc[4];
#pragma unroll
    for (int t = 0; t < 4; ++t) acc[t] = (f32x4){0.f, 0.f, 0.f, 0.f};

    for (int kc = 0; kc < 4; ++kc) {
        half8 Ah = *(const half8*)(Xh + rowA * 136 + kc * 32 + quad * 8);
#pragma unroll
        for (int nt = 0; nt < 4; ++nt) {
            half8 Bv = *(const half8*)(Bh + (((size_t)((ntb + nt) * 4 + kc)) * 64 + lane) * 8);
            acc[nt] = __builtin_amdgcn_mfma_f32_16x16x32_f16(Ah, Bv, acc[nt], 0, 0, 0);
        }
    }
    __syncthreads();

    int rowD0 = (wid & 1) * 16 + quad * 4;
#pragma unroll
    for (int nt = 0; nt < 4; ++nt)
#pragma unroll
        for (int r = 0; r < 4; ++r)
            Hs[(rowD0 + r) * 136 + (ntb + nt) * 16 + l16] = acc[nt][r];
    __syncthreads();

    const float4* Hs4 = (const float4*)Hs;
    half4* H4 = (half4*)Hout;
#pragma unroll
    for (int i = 0; i < 4; ++i) {
        int idx = i * 256 + tid;
        int row = idx >> 5, c4 = idx & 31;
        int grow = base + row;
        if (grow < n) {
            float4 v = Hs4[row * 34 + c4];
            half4 hv = {(_Float16)v.x, (_Float16)v.y, (_Float16)v.z, (_Float16)v.w};
            H4[(size_t)grow * 32 + c4] = hv;
        }
    }

    // dots (fp32 from LDS): thread -> row tid>>3, eighth tid&7, reduce over 8 lanes
    int drow = tid >> 3, q = tid & 7;
    const float4* as4 = (const float4*)a_s;
    const float4* ad4 = (const float4*)a_d;
    float s = 0.f, d = 0.f;
#pragma unroll
    for (int j = 0; j < 4; ++j) {
        float4 v = Hs4[drow * 34 + q * 4 + j];
        float4 a = as4[q * 4 + j];
        float4 b = ad4[q * 4 + j];
        s += v.x * a.x + v.y * a.y + v.z * a.z + v.w * a.w;
        d += v.x * b.x + v.y * b.y + v.z * b.z + v.w * b.w;
    }
    s += __shfl_xor(s, 1, WAVE); s += __shfl_xor(s, 2, WAVE); s += __shfl_xor(s, 4, WAVE);
    d += __shfl_xor(d, 1, WAVE); d += __shfl_xor(d, 2, WAVE); d += __shfl_xor(d, 4, WAVE);
    if (q == 0 && base + drow < n) {
        as_[base + drow] = s;
        ad_[base + drow] = d;
    }
}

__device__ __forceinline__ float leaky02(float x) { return x > 0.f ? x : 0.2f * x; }

// ---------------- GAT aggregation: EXACT r15 kernel (measured 54.2us) ----------------
// DO NOT append epilogues or params (r9/r10 codegen-poison lesson). Half-wave
// per edge; fp16 h gather (half4, 8B/lane), fp32 accumulate.
__global__ __launch_bounds__(256) void gat_aggregate(const _Float16* __restrict__ h,
                                                     const float* __restrict__ as_,
                                                     const float* __restrict__ ad_,
                                                     const int* __restrict__ csr_src,
                                                     const int* __restrict__ offs,
                                                     const float* __restrict__ bias,
                                                     float* __restrict__ out, int n, int act) {
    int node = blockIdx.x * 4 + (threadIdx.x >> 6);
    int lane = threadIdx.x & 63;
    if (node >= n) return;
    int beg = offs[node], end = offs[node + 1];
    float adn = ad_[node];
    int half = lane >> 5;
    int l = lane & 31;
    const half4* h4 = (const half4*)h;

    float w_self = __expf(leaky02(as_[node] + adn));
    float4 acc;
    float sacc;
    {
        float ws = (half == 0) ? w_self : 0.f;
        half4 v = h4[(size_t)node * 32 + l];
        acc.x = ws * (float)v.x; acc.y = ws * (float)v.y;
        acc.z = ws * (float)v.z; acc.w = ws * (float)v.w;
        sacc = (lane == 0) ? w_self : 0.f;
    }
#pragma unroll 4
    for (int j = beg; j < end; j += 2) {
        int j0 = j + half;
        bool valid = j0 < end;
        int s = valid ? csr_src[j0] : node;
        float w = valid ? __expf(leaky02(as_[s] + adn)) : 0.f;
        half4 v = h4[(size_t)s * 32 + l];
        acc.x = fmaf(w, (float)v.x, acc.x);
        acc.y = fmaf(w, (float)v.y, acc.y);
        acc.z = fmaf(w, (float)v.z, acc.z);
        acc.w = fmaf(w, (float)v.w, acc.w);
        sacc += (l == 0) ? w : 0.f;
    }
    acc.x += __shfl_xor(acc.x, 32, WAVE);
    acc.y += __shfl_xor(acc.y, 32, WAVE);
    acc.z += __shfl_xor(acc.z, 32, WAVE);
    acc.w += __shfl_xor(acc.w, 32, WAVE);
    sacc += __shfl_xor(sacc, 32, WAVE);
    float stot = __shfl(sacc, 0, WAVE);
    float inv_s = 1.f / stot;
    if (half == 0) {
        float4 b = ((const float4*)bias)[l];
        float4 o;
        o.x = fmaf(acc.x, inv_s, b.x);
        o.y = fmaf(acc.y, inv_s, b.y);
        o.z = fmaf(acc.z, inv_s, b.z);
        o.w = fmaf(acc.w, inv_s, b.w);
        if (act == 1) {
            o.x = o.x > 0.f ? o.x : expm1f(o.x);
            o.y = o.y > 0.f ? o.y : expm1f(o.y);
            o.z = o.z > 0.f ? o.z : expm1f(o.z);
            o.w = o.w > 0.f ? o.w : expm1f(o.w);
        }
        ((float4*)(out + (size_t)node * 128))[l] = o;
    }
}

// ---------------- energy via fp16 MFMA, GR=32 ----------------
__global__ __launch_bounds__(256) void energy_mfma(const float* __restrict__ X,
                                                   const _Float16* __restrict__ Ph,
                                                   const float* __restrict__ bp1,
                                                   const float* __restrict__ Wp2,
                                                   const float* __restrict__ bp2,
                                                   float* __restrict__ energy, int n, int HP) {
    __shared__ _Float16 Xh[GR * 136];   // 8704 B
    int tid = threadIdx.x;
    int base = blockIdx.x * GR;
    const float4* X4 = (const float4*)X;
#pragma unroll
    for (int i = 0; i < 4; ++i) {
        int idx = i * 256 + tid;
        int row = idx >> 5, c4 = idx & 31;
        int rs = base + row; if (rs >= n) rs = n - 1;
        float4 v = X4[(size_t)rs * 32 + c4];
        half4 hv = {(_Float16)v.x, (_Float16)v.y, (_Float16)v.z, (_Float16)v.w};
        *(half4*)(Xh + row * 136 + c4 * 4) = hv;
    }
    __syncthreads();

    int wid = tid >> 6, lane = tid & 63;
    if (wid >= 2) return;   // waves 2,3 done after staging
    int quad = lane >> 4, l16 = lane & 15;
    int rowA = wid * 16 + l16;

    f32x4 acc0 = (f32x4){0.f, 0.f, 0.f, 0.f};
    f32x4 acc1 = (f32x4){0.f, 0.f, 0.f, 0.f};
    for (int kc = 0; kc < 4; ++kc) {
        half8 Ah = *(const half8*)(Xh + rowA * 136 + kc * 32 + quad * 8);
        half8 B0 = *(const half8*)(Ph + (((size_t)kc) * 64 + lane) * 8);
        half8 B1 = *(const half8*)(Ph + (((size_t)(4 + kc)) * 64 + lane) * 8);
        acc0 = __builtin_amdgcn_mfma_f32_16x16x32_f16(Ah, B0, acc0, 0, 0, 0);
        acc1 = __builtin_amdgcn_mfma_f32_16x16x32_f16(Ah, B1, acc1, 0, 0, 0);
    }

    float b0 = bp1[l16];
    float w0 = Wp2[l16];
    int c1 = 16 + l16;
    int c1c = c1 < HP ? c1 : HP - 1;
    float b1 = bp1[c1c];
    float w1 = (c1 < HP) ? Wp2[c1c] : 0.f;
    float bp2v = bp2[0];
#pragma unroll
    for (int r = 0; r < 4; ++r) {
        float h0 = acc0[r] + b0;
        h0 = h0 > 0.f ? h0 : 0.f;
        float h1 = acc1[r] + b1;
        h1 = h1 > 0.f ? h1 : 0.f;
        float v = h0 * w0 + h1 * w1;
        v += __shfl_xor(v, 1, WAVE);
        v += __shfl_xor(v, 2, WAVE);
        v += __shfl_xor(v, 4, WAVE);
        v += __shfl_xor(v, 8, WAVE);
        int row = base + wid * 16 + quad * 4 + r;
        if (l16 == 0 && row < n) energy[row] = v + bp2v;
    }
}

// ---------------- fused segment softmax-pool + classifier (r12, measured-good) ----------------
__global__ __launch_bounds__(256) void seg_pool_classify(const float* __restrict__ X,
                                                         const float* __restrict__ energy,
                                                         const int* __restrict__ node_pos,
                                                         const float* __restrict__ Wl,
                                                         const float* __restrict__ bl,
                                                         float* __restrict__ out, int C) {
    int g = blockIdx.x;
    int beg = node_pos[g], end = node_pos[g + 1];
    int tid = threadIdx.x;
    __shared__ float sred[256];
    __shared__ float4 red[256];
    __shared__ float pP[128];

    float m = -INFINITY;
    for (int i = beg + tid; i < end; i += 256) m = fmaxf(m, energy[i]);
    sred[tid] = m;
    __syncthreads();
    for (int o = 128; o > 0; o >>= 1) {
        if (tid < o) sred[tid] = fmaxf(sred[tid], sred[tid + o]);
        __syncthreads();
    }
    m = sred[0];
    __syncthreads();
    float s = 0.f;
    for (int i = beg + tid; i < end; i += 256) s += __expf(energy[i] - m);
    sred[tid] = s;
    __syncthreads();
    for (int o = 128; o > 0; o >>= 1) {
        if (tid < o) sred[tid] += sred[tid + o];
        __syncthreads();
    }
    s = sred[0];
    __syncthreads();
    float inv = (end > beg && s > 0.f) ? 1.f / s : 0.f;

    int quad = tid & 31;
    int rg = tid >> 5;
    const float4* X4 = (const float4*)X;
    float4 acc = make_float4(0.f, 0.f, 0.f, 0.f);
    for (int i = beg + rg; i < end; i += 8) {
        float w = __expf(energy[i] - m) * inv;
        float4 v = X4[(size_t)i * 32 + quad];
        acc.x = fmaf(w, v.x, acc.x);
        acc.y = fmaf(w, v.y, acc.y);
        acc.z = fmaf(w, v.z, acc.z);
        acc.w = fmaf(w, v.w, acc.w);
    }
    red[tid] = acc;
    __syncthreads();
    if (rg < 4) {
        float4 o = red[tid + 128];
        acc.x += o.x; acc.y += o.y; acc.z += o.z; acc.w += o.w;
        red[tid] = acc;
    }
    __syncthreads();
    if (rg < 2) {
        float4 o = red[tid + 64];
        acc.x += o.x; acc.y += o.y; acc.z += o.z; acc.w += o.w;
        red[tid] = acc;
    }
    __syncthreads();
    if (rg == 0) {
        float4 o = red[tid + 32];
        acc.x += o.x; acc.y += o.y; acc.z += o.z; acc.w += o.w;
        pP[4 * quad + 0] = acc.x;
        pP[4 * quad + 1] = acc.y;
        pP[4 * quad + 2] = acc.z;
        pP[4 * quad + 3] = acc.w;
    }
    __syncthreads();

    for (int c = tid; c < C; c += 256) {
        float a = bl[c];
#pragma unroll 8
        for (int k = 0; k < 128; ++k) a = fmaf(pP[k], Wl[(size_t)k * C + c], a);
        out[(size_t)g * C + c] = a;
    }
}

extern "C" void kernel_launch(void* const* d_in, const int* in_sizes, int n_in,
                              void* d_out, int out_size, void* d_ws, size_t ws_size,
                              hipStream_t stream) {
    const float* cfg_nodes = (const float*)d_in[0];
    const int* rel = (const int*)d_in[1];
    const int* node_pos = (const int*)d_in[2];
    const float* W_g1 = (const float*)d_in[3];
    const float* att_src1 = (const float*)d_in[4];
    const float* att_dst1 = (const float*)d_in[5];
    const float* b_g1 = (const float*)d_in[6];
    const float* W_g2 = (const float*)d_in[7];
    const float* att_src2 = (const float*)d_in[8];
    const float* att_dst2 = (const float*)d_in[9];
    const float* b_g2 = (const float*)d_in[10];
    const float* Wp1 = (const float*)d_in[11];
    const float* bp1 = (const float*)d_in[12];
    const float* Wp2 = (const float*)d_in[13];
    const float* bp2 = (const float*)d_in[14];
    const float* Wl = (const float*)d_in[15];
    const float* bl = (const float*)d_in[16];

    const int N = in_sizes[0] / 128;
    const int E = in_sizes[1] / 2;
    const int G = in_sizes[2] - 1;
    const int HP = in_sizes[12];
    const int C = out_size / G;

    const int* srcArr = rel;
    const int* dstArr = rel + E;

    char* w = (char*)d_ws;
    auto carve = [&](size_t bytes) -> char* {
        char* p = w;
        w += (bytes + 255) & ~(size_t)255;
        return p;
    };
    _Float16* bufH = (_Float16*)carve((size_t)N * 128 * 2);   // fp16 gemm output (gat gather src)
    float* bufB = (float*)carve((size_t)N * 128 * 4);
    float* asv = (float*)carve((size_t)N * 4);
    float* adv = (float*)carve((size_t)N * 4);
    float* energy = (float*)carve((size_t)N * 4);
    int* deg = (int*)carve((size_t)N * 4);
    int* offs = (int*)carve((size_t)(N + 1) * 4);
    int* cursor = (int*)carve((size_t)N * 4);
    int* csr_src = (int*)carve((size_t)E * 4);
    int* bsums = (int*)carve(1024);
    _Float16* W1h = (_Float16*)carve(16384 * 2);
    _Float16* W2h = (_Float16*)carve(16384 * 2);
    _Float16* Ph = (_Float16*)carve(4096 * 2);

    const int nbN = (N + 255) / 256;
    const int nbC = ((E + 1) / 2 + 255) / 256;   // 2 edges per thread
    const int nbT = (N + GR - 1) / GR;           // GR=32 -> 1563 blocks

    // ---- CSR build + W/Wp1 pack ----
    hipMemsetAsync(deg, 0, (size_t)N * 4, stream);
    count_pack<<<nbC + 144, 256, 0, stream>>>(dstArr, deg, E, nbC,
                                              W_g1, W_g2, W1h, W2h, Wp1, HP, Ph);
    scan_block<<<nbN, 256, 0, stream>>>(deg, offs, bsums, N);
    scan_finish<<<nbN, 256, 0, stream>>>(offs, bsums, offs, cursor, N, E);
    scatter_edges<<<nbC, 256, 0, stream>>>(srcArr, dstArr, cursor, csr_src, E);

    // ---- GAT layer 1 ----
    gemm_mfma<<<nbT, 256, 0, stream>>>(cfg_nodes, W1h, att_src1, att_dst1,
                                       bufH, asv, adv, N);
    gat_aggregate<<<(N + 3) / 4, 256, 0, stream>>>(bufH, asv, adv, csr_src, offs, b_g1, bufB, N, 1);

    // ---- GAT layer 2 ----
    gemm_mfma<<<nbT, 256, 0, stream>>>(bufB, W2h, att_src2, att_dst2,
                                       bufH, asv, adv, N);
    gat_aggregate<<<(N + 3) / 4, 256, 0, stream>>>(bufH, asv, adv, csr_src, offs, b_g2, bufB, N, 0);

    // ---- energy (fp16 MFMA) + pooling + classifier ----
    energy_mfma<<<nbT, 256, 0, stream>>>(bufB, Ph, bp1, Wp2, bp2, energy, N, HP);
    seg_pool_classify<<<G, 256, 0, stream>>>(bufB, energy, node_pos, Wl, bl, (float*)d_out, C);
}